// Round 6
// baseline (131.310 us; speedup 1.0000x reference)
//
#include <hip/hip_runtime.h>

// Problem constants (from reference)
#define BB   4
#define N1   1024
#define DIM  1024
#define FF   4
#define NN   1025           // N1 + 1
#define NTOT (FF * NN)      // 4100
#define SIM_TOTAL ((size_t)BB * N1 * NTOT)   // 16,793,600 floats
#define NEGV (-1e9f)

typedef float vfloat4 __attribute__((ext_vector_type(4)));

// ---------------------------------------------------------------------------
// One WAVE per row (b,i). No LDS, no barriers, 1 launch.
// Structure (latency-overlap version):
//   1. issue ALL 20 float4 loads (4 lhs + 16 rhs)    -- needs ~80 data VGPRs,
//      enabled by __launch_bounds__(256,4) (128-VGPR budget; grid gives
//      exactly 4 waves/SIMD so occupancy is unchanged)
//   2. while loads are in flight, stream the row's -1e9 fill, SKIPPING the
//      4 float4 slots that contain kept columns (no dependency on loads)
//   3. waitcnt (compiler-inserted), FMAs, butterfly-reduce 9 scalars
//   4. owner lanes write the 4 patched float4 slots; lane 0 writes lhs_norm
// ---------------------------------------------------------------------------
__global__ __launch_bounds__(256, 4)
void lcs_kernel(const float* __restrict__ lhs,
                const float* __restrict__ rhs,
                float* __restrict__ out) {
    const int row  = blockIdx.x * 4 + (threadIdx.x >> 6);  // 0 .. B*N1-1
    const int lane = threadIdx.x & 63;
    const int b    = row >> 10;          // / N1
    const int i    = row & (N1 - 1);     // % N1

    // ---- kept columns / slots for this row ----
    int q[FF], s[FF];
#pragma unroll
    for (int f = 0; f < FF; ++f) {
        q[f] = f * NN + (i + 1);         // kept column within row (dword idx)
        s[f] = q[f] >> 2;                // float4 slot containing it
    }

    // ---- 1. issue all loads ----
    const float4* lrow = (const float4*)(lhs + (size_t)row * DIM);
    float4 lv[4];
#pragma unroll
    for (int k = 0; k < 4; ++k)
        lv[k] = lrow[lane + 64 * k];

    float4 rv[FF][4];
#pragma unroll
    for (int f = 0; f < FF; ++f) {
        const float4* rrow = (const float4*)(rhs +
            ((size_t)b * NTOT + (size_t)f * NN + (i + 1)) * DIM);
#pragma unroll
        for (int k = 0; k < 4; ++k)
            rv[f][k] = rrow[lane + 64 * k];
    }

    // ---- 2. stream -1e9 fill while loads are in flight ----
    vfloat4* orow4 = (vfloat4*)(out + (size_t)row * NTOT);  // 16B-aligned
    vfloat4 neg4;
    neg4.x = NEGV; neg4.y = NEGV; neg4.z = NEGV; neg4.w = NEGV;
    for (int k = lane; k <= 1024; k += 64) {                // lane 0 takes 1024
        const bool skip = (k == s[0]) | (k == s[1]) | (k == s[2]) | (k == s[3]);
        if (!skip)
            __builtin_nontemporal_store(neg4, &orow4[k]);
    }

    // ---- 3. partials + butterfly reduce ----
    float l2 = 0.f;
#pragma unroll
    for (int k = 0; k < 4; ++k)
        l2 += lv[k].x * lv[k].x + lv[k].y * lv[k].y +
              lv[k].z * lv[k].z + lv[k].w * lv[k].w;

    float dotf[FF], r2f[FF];
#pragma unroll
    for (int f = 0; f < FF; ++f) {
        float d = 0.f, r2 = 0.f;
#pragma unroll
        for (int k = 0; k < 4; ++k) {
            d  += lv[k].x * rv[f][k].x + lv[k].y * rv[f][k].y +
                  lv[k].z * rv[f][k].z + lv[k].w * rv[f][k].w;
            r2 += rv[f][k].x * rv[f][k].x + rv[f][k].y * rv[f][k].y +
                  rv[f][k].z * rv[f][k].z + rv[f][k].w * rv[f][k].w;
        }
        dotf[f] = d;
        r2f[f]  = r2;
    }

#pragma unroll
    for (int off = 1; off < 64; off <<= 1) {
        l2 += __shfl_xor(l2, off, 64);
#pragma unroll
        for (int f = 0; f < FF; ++f) {
            dotf[f] += __shfl_xor(dotf[f], off, 64);
            r2f[f]  += __shfl_xor(r2f[f],  off, 64);
        }
    }

    // ---- 4. patched slots + norm ----
#pragma unroll
    for (int f = 0; f < FF; ++f) {
        if (lane == (s[f] & 63)) {
            const float sim = (dotf[f] * dotf[f]) / (l2 * r2f[f]);
            const int   p   = q[f] & 3;
            vfloat4 v;
            v.x = (p == 0) ? sim : NEGV;
            v.y = (p == 1) ? sim : NEGV;
            v.z = (p == 2) ? sim : NEGV;
            v.w = (p == 3) ? sim : NEGV;
            __builtin_nontemporal_store(v, &orow4[s[f]]);
        }
    }

    if (lane == 0)
        out[SIM_TOTAL + row] = sqrtf(l2);   // lhs_norm (B, N1, 1)
}

extern "C" void kernel_launch(void* const* d_in, const int* in_sizes, int n_in,
                              void* d_out, int out_size, void* d_ws, size_t ws_size,
                              hipStream_t stream) {
    const float* lhs = (const float*)d_in[0];  // (B, N1, DIM)
    const float* rhs = (const float*)d_in[1];  // (B, NTOT, DIM)
    float* out = (float*)d_out;                // sim (B,N1,NTOT) ++ lhs_norm (B,N1,1)

    lcs_kernel<<<(BB * N1) / 4, 256, 0, stream>>>(lhs, rhs, out);
}